// Round 1
// baseline (662.636 us; speedup 1.0000x reference)
//
#include <hip/hip_runtime.h>
#include <math.h>

#define NWG 256      // waveguides (N)
#define NPAIR 128    // pairs per layer
#define NITER 3
#define NBATCH 8192
#define WROWS 4      // rows per wave

// y0 = A*x0 + B*x1 ; y1 = C*x0 + D*x1   (complex, A..D packed in two float4)
static __device__ __forceinline__ void apply2(
    float &x0r, float &x0i, float &x1r, float &x1i,
    const float4 a, const float4 b)
{
    float y0r = a.x*x0r - a.y*x0i + a.z*x1r - a.w*x1i;
    float y0i = a.x*x0i + a.y*x0r + a.z*x1i + a.w*x1r;
    float y1r = b.x*x0r - b.y*x0i + b.z*x1r - b.w*x1i;
    float y1i = b.x*x0i + b.y*x0r + b.z*x1i + b.w*x1r;
    x0r = y0r; x0i = y0i; x1r = y1r; x1i = y1i;
}

// coef layout: [iter][layer][pair] -> {Ar,Ai,Br,Bi, Cr,Ci,Dr,Di} (2 float4)
// gexp layout: [iter][n] -> {cos(g), sin(g)}
__global__ void precompute_kernel(const float* __restrict__ theta,
                                  const float* __restrict__ phi,
                                  const float* __restrict__ gamma,
                                  float* __restrict__ coef,
                                  float* __restrict__ gexp)
{
    int idx = blockIdx.x * blockDim.x + threadIdx.x;
    if (idx < NITER * NWG * NPAIR) {
        float h  = 0.5f * theta[idx];
        float ph = phi[idx];
        float sh = sinf(h),  ch = cosf(h);
        float sp = sinf(ph), cp = cosf(ph);
        // pre = i*exp(i*h) = (-sh, ch) ; preep = pre*exp(i*ph)
        float pr = -sh, pii = ch;
        float qr = pr*cp - pii*sp;
        float qi = pr*sp + pii*cp;
        float4 ab, cd;
        ab.x = qr*sh;  ab.y = qi*sh;    // A = preep*s
        ab.z = pr*ch;  ab.w = pii*ch;   // B = pre*c
        cd.x = qr*ch;  cd.y = qi*ch;    // C = preep*c
        cd.z = -pr*sh; cd.w = -pii*sh;  // D = -pre*s
        float4* o = (float4*)coef + (size_t)idx * 2;
        o[0] = ab; o[1] = cd;
    }
    if (idx < NITER * NWG) {
        float g = gamma[idx];
        gexp[idx*2]   = cosf(g);
        gexp[idx*2+1] = sinf(g);
    }
}

__global__ __launch_bounds__(256, 2) void mzi_main(
    const float* __restrict__ x_real, const float* __restrict__ x_imag,
    const float* __restrict__ coef, const float* __restrict__ gexp,
    float* __restrict__ out)
{
    const int lane = threadIdx.x & 63;
    const int wv   = threadIdx.x >> 6;
    const int row0 = (blockIdx.x * 4 + wv) * WROWS;

    // lane l holds complex elements 4l..4l+3 of WROWS rows
    float xr[WROWS][4], xi[WROWS][4];
#pragma unroll
    for (int r = 0; r < WROWS; ++r) {
        float4 vr = *(const float4*)(x_real + (size_t)(row0 + r) * NWG + lane * 4);
        float4 vi = *(const float4*)(x_imag + (size_t)(row0 + r) * NWG + lane * 4);
        xr[r][0]=vr.x; xr[r][1]=vr.y; xr[r][2]=vr.z; xr[r][3]=vr.w;
        xi[r][0]=vi.x; xi[r][1]=vi.y; xi[r][2]=vi.z; xi[r][3]=vi.w;
    }

    for (int it = 0; it < NITER; ++it) {
        const float4* cb = (const float4*)coef + (size_t)it * NWG * NPAIR * 2;
        // preload layer 0 coefficients: pairs 2*lane and 2*lane+1 (64 B contiguous)
        const float4* pb = cb + ((size_t)0 * NPAIR + 2 * lane) * 2;
        float4 c0a = pb[0], c0b = pb[1], c1a = pb[2], c1b = pb[3];

        for (int t = 0; t < NWG; ++t) {
            // prefetch next layer's coefficients (clamped at end; uniform branch-free)
            int tn = (t + 1 < NWG) ? t + 1 : t;
            const float4* nb = cb + ((size_t)tn * NPAIR + 2 * lane) * 2;
            float4 n0a = nb[0], n0b = nb[1], n1a = nb[2], n1b = nb[3];

            if ((t & 1) == 0) {
                // even layer: pairs (4l,4l+1) and (4l+2,4l+3) — intra-lane
#pragma unroll
                for (int r = 0; r < WROWS; ++r) {
                    apply2(xr[r][0], xi[r][0], xr[r][1], xi[r][1], c0a, c0b);
                    apply2(xr[r][2], xi[r][2], xr[r][3], xi[r][3], c1a, c1b);
                }
            } else {
                // odd layer: pair 2l on (4l+1,4l+2); pair 2l+1 on (4l+3, 4l+4 from lane l+1)
                // pair 127 (lane 63's second pair, the wrap pair) is inactive.
#pragma unroll
                for (int r = 0; r < WROWS; ++r) {
                    float tr = __shfl_down(xr[r][0], 1, 64);
                    float ti = __shfl_down(xi[r][0], 1, 64);
                    apply2(xr[r][1], xi[r][1], xr[r][2], xi[r][2], c0a, c0b);
                    float x3r = xr[r][3], x3i = xi[r][3];
                    float y3r = c1a.x*x3r - c1a.y*x3i + c1a.z*tr - c1a.w*ti;
                    float y3i = c1a.x*x3i + c1a.y*x3r + c1a.z*ti + c1a.w*tr;
                    float ynr = c1b.x*x3r - c1b.y*x3i + c1b.z*tr - c1b.w*ti;
                    float yni = c1b.x*x3i + c1b.y*x3r + c1b.z*ti + c1b.w*tr;
                    float rr = __shfl_up(ynr, 1, 64);
                    float ri = __shfl_up(yni, 1, 64);
                    if (lane != 63) { xr[r][3] = y3r; xi[r][3] = y3i; }
                    if (lane != 0)  { xr[r][0] = rr;  xi[r][0] = ri; }
                }
            }
            c0a = n0a; c0b = n0b; c1a = n1a; c1b = n1b;
        }

        // output phases: x *= exp(i*gamma)
        const float4* gb4 = (const float4*)(gexp + (size_t)it * NWG * 2) + lane * 2;
        float4 g0 = gb4[0], g1 = gb4[1];
        float gc[4] = {g0.x, g0.z, g1.x, g1.z};
        float gs[4] = {g0.y, g0.w, g1.y, g1.w};
#pragma unroll
        for (int r = 0; r < WROWS; ++r) {
#pragma unroll
            for (int e = 0; e < 4; ++e) {
                float a = xr[r][e], b = xi[r][e];
                xr[r][e] = a*gc[e] - b*gs[e];
                xi[r][e] = a*gs[e] + b*gc[e];
            }
        }

        if (it != NITER - 1) {
            // EO nonlinearity: phase = 0.5*G*|x|^2 + 0.5*phi_b
            // out = sqrt(1-alpha)*cos(phase)*exp(-i*phase)*x
            const float k = 0.94868329805051381f;  // sqrt(0.9)
#pragma unroll
            for (int r = 0; r < WROWS; ++r) {
#pragma unroll
                for (int e = 0; e < 4; ++e) {
                    float a = xr[r][e], b = xi[r][e];
                    float I = a*a + b*b;
                    float phase = 0.078539816339744831f * I + 1.5707963267948966f;
                    float sp, cp;
                    __sincosf(phase, &sp, &cp);
                    float f = k * cp;
                    xr[r][e] = f*(cp*a + sp*b);
                    xi[r][e] = f*(cp*b - sp*a);
                }
            }
        }
    }

    // intensity, per-row L2 normalization of intensity vector, emit first 10
#pragma unroll
    for (int r = 0; r < WROWS; ++r) {
        float I0 = xr[r][0]*xr[r][0] + xi[r][0]*xi[r][0];
        float I1 = xr[r][1]*xr[r][1] + xi[r][1]*xi[r][1];
        float I2 = xr[r][2]*xr[r][2] + xi[r][2]*xi[r][2];
        float I3 = xr[r][3]*xr[r][3] + xi[r][3]*xi[r][3];
        float ss = I0*I0 + I1*I1 + I2*I2 + I3*I3;
#pragma unroll
        for (int d = 1; d < 64; d <<= 1) ss += __shfl_xor(ss, d, 64);
        float inv = 1.0f / fmaxf(sqrtf(ss), 1e-12f);
        float* o = out + (size_t)(row0 + r) * 10;
        if (lane == 0)      { o[0]=I0*inv; o[1]=I1*inv; o[2]=I2*inv; o[3]=I3*inv; }
        else if (lane == 1) { o[4]=I0*inv; o[5]=I1*inv; o[6]=I2*inv; o[7]=I3*inv; }
        else if (lane == 2) { o[8]=I0*inv; o[9]=I1*inv; }
    }
}

extern "C" void kernel_launch(void* const* d_in, const int* in_sizes, int n_in,
                              void* d_out, int out_size, void* d_ws, size_t ws_size,
                              hipStream_t stream)
{
    const float* x_real = (const float*)d_in[0];
    const float* x_imag = (const float*)d_in[1];
    const float* theta  = (const float*)d_in[2];
    const float* phi    = (const float*)d_in[3];
    const float* gamma  = (const float*)d_in[4];

    float* coef = (float*)d_ws;                                   // 3*256*128*8 floats = 3 MB
    float* gexp = coef + (size_t)NITER * NWG * NPAIR * 8;         // 3*256*2 floats

    precompute_kernel<<<(NITER * NWG * NPAIR + 255) / 256, 256, 0, stream>>>(
        theta, phi, gamma, coef, gexp);

    mzi_main<<<NBATCH / (4 * WROWS), 256, 0, stream>>>(
        x_real, x_imag, coef, gexp, (float*)d_out);
}

// Round 2
// 244.986 us; speedup vs baseline: 2.7048x; 2.7048x over previous
//
#include <hip/hip_runtime.h>
#include <math.h>

#define NWG 256      // waveguides (N)
#define NPAIR 128    // pairs per layer
#define NITER 3
#define NBATCH 8192
#define KDIM 512     // 2*NWG (real embedding of complex)

typedef __attribute__((ext_vector_type(8))) short short8;   // 8 bf16
typedef __attribute__((ext_vector_type(4))) float floatx4;  // MFMA acc

static __device__ __forceinline__ unsigned short f2bf(float f) {
    unsigned int u = __float_as_uint(f);
    unsigned int r = (u + 0x7fffu + ((u >> 16) & 1u)) >> 16;  // RNE
    return (unsigned short)r;
}

// y0 = A*x0 + B*x1 ; y1 = C*x0 + D*x1   (complex; a=(Ar,Ai,Br,Bi) b=(Cr,Ci,Dr,Di))
static __device__ __forceinline__ void apply2(
    float &x0r, float &x0i, float &x1r, float &x1i,
    const float4 a, const float4 b)
{
    float y0r = a.x*x0r - a.y*x0i + a.z*x1r - a.w*x1i;
    float y0i = a.x*x0i + a.y*x0r + a.z*x1i + a.w*x1r;
    float y1r = b.x*x0r - b.y*x0i + b.z*x1r - b.w*x1i;
    float y1i = b.x*x0i + b.y*x0r + b.z*x1i + b.w*x1r;
    x0r = y0r; x0i = y0i; x1r = y1r; x1i = y1i;
}

// coef: [iter][layer][pair] -> {Ar,Ai,Br,Bi, Cr,Ci,Dr,Di} ; gexp: [iter][n] -> {cos g, sin g}
__global__ void precompute_kernel(const float* __restrict__ theta,
                                  const float* __restrict__ phi,
                                  const float* __restrict__ gamma,
                                  float* __restrict__ coef,
                                  float* __restrict__ gexp)
{
    int idx = blockIdx.x * blockDim.x + threadIdx.x;
    if (idx < NITER * NWG * NPAIR) {
        float h  = 0.5f * theta[idx];
        float ph = phi[idx];
        float sh = sinf(h),  ch = cosf(h);
        float sp = sinf(ph), cp = cosf(ph);
        float pr = -sh, pii = ch;              // pre = i*exp(i*h)
        float qr = pr*cp - pii*sp;             // preep = pre*exp(i*ph)
        float qi = pr*sp + pii*cp;
        float4 ab, cd;
        ab.x = qr*sh;  ab.y = qi*sh;    // A
        ab.z = pr*ch;  ab.w = pii*ch;   // B
        cd.x = qr*ch;  cd.y = qi*ch;    // C
        cd.z = -pr*sh; cd.w = -pii*sh;  // D
        float4* o = (float4*)coef + (size_t)idx * 2;
        o[0] = ab; o[1] = cd;
    }
    if (idx < NITER * NWG) {
        float g = gamma[idx];
        gexp[idx*2]   = cosf(g);
        gexp[idx*2+1] = sinf(g);
    }
}

// Propagate M^T e_n (reverse layers, transposed 2x2, gamma first) -> row n of M.
// Writes real-embedded transposed GEMM B: Bmat[n][k<256]=Re M[n][k],
// [n][k+256]=-Im, [n+256][k]=Im, [n+256][k+256]=Re. Fully coalesced.
__global__ void propagate_kernel(const float* __restrict__ coef,
                                 const float* __restrict__ gexp,
                                 unsigned short* __restrict__ Bmat)
{
    const int lane = threadIdx.x & 63;
    const int wv   = threadIdx.x >> 6;
    const int it   = blockIdx.x >> 5;        // 32 blocks per iteration
    const int rb   = blockIdx.x & 31;
    const int row0 = rb * 8 + wv * 2;        // 2 rows (of M) per wave

    float xr[2][4], xi[2][4];
#pragma unroll
    for (int r = 0; r < 2; ++r) {
        int n = row0 + r;
        float gc = gexp[(it * NWG + n) * 2];
        float gs = gexp[(it * NWG + n) * 2 + 1];
#pragma unroll
        for (int e = 0; e < 4; ++e) {
            int comp = 4 * lane + e;
            xr[r][e] = (comp == n) ? gc : 0.0f;
            xi[r][e] = (comp == n) ? gs : 0.0f;
        }
    }

    const float4* cb = (const float4*)coef + (size_t)it * NWG * NPAIR * 2;
    const float4* pb = cb + ((size_t)255 * NPAIR + 2 * lane) * 2;
    float4 c0a = pb[0], c0b = pb[1], c1a = pb[2], c1b = pb[3];

    for (int t = 255; t >= 0; --t) {
        int tn = (t > 0) ? t - 1 : 0;
        const float4* nb = cb + ((size_t)tn * NPAIR + 2 * lane) * 2;
        float4 n0a = nb[0], n0b = nb[1], n1a = nb[2], n1b = nb[3];

        // transposed 2x2: rows (A,C) and (B,D)
        float4 t0a, t0b, t1a, t1b;
        t0a.x=c0a.x; t0a.y=c0a.y; t0a.z=c0b.x; t0a.w=c0b.y;
        t0b.x=c0a.z; t0b.y=c0a.w; t0b.z=c0b.z; t0b.w=c0b.w;
        t1a.x=c1a.x; t1a.y=c1a.y; t1a.z=c1b.x; t1a.w=c1b.y;
        t1b.x=c1a.z; t1b.y=c1a.w; t1b.z=c1b.z; t1b.w=c1b.w;

        if ((t & 1) == 0) {
#pragma unroll
            for (int r = 0; r < 2; ++r) {
                apply2(xr[r][0], xi[r][0], xr[r][1], xi[r][1], t0a, t0b);
                apply2(xr[r][2], xi[r][2], xr[r][3], xi[r][3], t1a, t1b);
            }
        } else {
#pragma unroll
            for (int r = 0; r < 2; ++r) {
                float tr = __shfl_down(xr[r][0], 1, 64);
                float ti = __shfl_down(xi[r][0], 1, 64);
                apply2(xr[r][1], xi[r][1], xr[r][2], xi[r][2], t0a, t0b);
                float x3r = xr[r][3], x3i = xi[r][3];
                float y3r = t1a.x*x3r - t1a.y*x3i + t1a.z*tr - t1a.w*ti;
                float y3i = t1a.x*x3i + t1a.y*x3r + t1a.z*ti + t1a.w*tr;
                float ynr = t1b.x*x3r - t1b.y*x3i + t1b.z*tr - t1b.w*ti;
                float yni = t1b.x*x3i + t1b.y*x3r + t1b.z*ti + t1b.w*tr;
                float rr = __shfl_up(ynr, 1, 64);
                float ri = __shfl_up(yni, 1, 64);
                if (lane != 63) { xr[r][3] = y3r; xi[r][3] = y3i; }
                if (lane != 0)  { xr[r][0] = rr;  xi[r][0] = ri; }
            }
        }
        c0a = n0a; c0b = n0b; c1a = n1a; c1b = n1b;
    }

    unsigned short* base = Bmat + (size_t)it * KDIM * KDIM;
#pragma unroll
    for (int r = 0; r < 2; ++r) {
        int n = row0 + r;
        ushort4 re, im, nim;
        re.x = f2bf(xr[r][0]); re.y = f2bf(xr[r][1]); re.z = f2bf(xr[r][2]); re.w = f2bf(xr[r][3]);
        im.x = f2bf(xi[r][0]); im.y = f2bf(xi[r][1]); im.z = f2bf(xi[r][2]); im.w = f2bf(xi[r][3]);
        nim.x = f2bf(-xi[r][0]); nim.y = f2bf(-xi[r][1]); nim.z = f2bf(-xi[r][2]); nim.w = f2bf(-xi[r][3]);
        *(ushort4*)(base + (size_t)n * KDIM + 4*lane)             = re;
        *(ushort4*)(base + (size_t)n * KDIM + 256 + 4*lane)       = nim;
        *(ushort4*)(base + (size_t)(n+256) * KDIM + 4*lane)       = im;
        *(ushort4*)(base + (size_t)(n+256) * KDIM + 256 + 4*lane) = re;
    }
}

__global__ void convert_kernel(const float* __restrict__ xre,
                               const float* __restrict__ xim,
                               unsigned short* __restrict__ xb)
{
    int idx = blockIdx.x * 256 + threadIdx.x;
    int b = idx >> 8, j = idx & 255;
    xb[(size_t)b * KDIM + j]       = f2bf(xre[idx]);
    xb[(size_t)b * KDIM + 256 + j] = f2bf(xim[idx]);
}

// C[8192][512] = A[8192][512] @ B^T-layout[512][512], bf16 in / fp32 out
#define BM 128
#define BN 128
#define BK 32
#define LDR 40   // padded LDS row (elems): 80 B keeps 16B align, 2-way banks max

__global__ __launch_bounds__(256) void gemm_kernel(
    const unsigned short* __restrict__ A,
    const unsigned short* __restrict__ B,
    float* __restrict__ C)
{
    __shared__ unsigned short As[BM * LDR];
    __shared__ unsigned short Bs[BN * LDR];

    const int tid  = threadIdx.x;
    const int lane = tid & 63;
    const int wv   = tid >> 6;
    const int wm   = (wv >> 1) * 64;
    const int wn   = (wv & 1) * 64;
    const int quad = lane >> 4;
    const int l16  = lane & 15;
    const int m0   = blockIdx.x * BM;
    const int n0   = blockIdx.y * BN;

    floatx4 acc[4][4] = {};

    const int srow = tid >> 2;
    const int schk = (tid & 3) * 8;

    for (int kt = 0; kt < KDIM; kt += BK) {
        __syncthreads();
#pragma unroll
        for (int h = 0; h < 2; ++h) {
            int r = srow + h * 64;
            *(short8*)(&As[r * LDR + schk]) =
                *(const short8*)(A + (size_t)(m0 + r) * KDIM + kt + schk);
            *(short8*)(&Bs[r * LDR + schk]) =
                *(const short8*)(B + (size_t)(n0 + r) * KDIM + kt + schk);
        }
        __syncthreads();

        short8 af[4], bfr[4];
#pragma unroll
        for (int i = 0; i < 4; ++i) {
            af[i]  = *(const short8*)(&As[(wm + i * 16 + l16) * LDR + quad * 8]);
            bfr[i] = *(const short8*)(&Bs[(wn + i * 16 + l16) * LDR + quad * 8]);
        }
#pragma unroll
        for (int mi = 0; mi < 4; ++mi)
#pragma unroll
            for (int ni = 0; ni < 4; ++ni)
                acc[mi][ni] = __builtin_amdgcn_mfma_f32_16x16x32_bf16(
                    af[mi], bfr[ni], acc[mi][ni], 0, 0, 0);
    }

#pragma unroll
    for (int mi = 0; mi < 4; ++mi)
#pragma unroll
        for (int ni = 0; ni < 4; ++ni) {
            int col = n0 + wn + ni * 16 + l16;
#pragma unroll
            for (int rg = 0; rg < 4; ++rg) {
                int row = m0 + wm + mi * 16 + quad * 4 + rg;
                C[(size_t)row * KDIM + col] = acc[mi][ni][rg];
            }
        }
}

__global__ void nonlin_kernel(const float* __restrict__ C,
                              unsigned short* __restrict__ xb)
{
    int idx = blockIdx.x * 256 + threadIdx.x;
    int b = idx >> 8, j = idx & 255;
    float a  = C[(size_t)b * KDIM + j];
    float bb = C[(size_t)b * KDIM + 256 + j];
    float I = a*a + bb*bb;
    float phase = 0.078539816339744831f * I + 1.5707963267948966f;
    float sp, cp;
    __sincosf(phase, &sp, &cp);
    float f = 0.94868329805051381f * cp;   // sqrt(0.9)*cos(phase)
    xb[(size_t)b * KDIM + j]       = f2bf(f*(cp*a + sp*bb));
    xb[(size_t)b * KDIM + 256 + j] = f2bf(f*(cp*bb - sp*a));
}

__global__ void final_kernel(const float* __restrict__ C,
                             float* __restrict__ out)
{
    const int lane = threadIdx.x & 63;
    const int wv   = threadIdx.x >> 6;
    const int row  = blockIdx.x * 4 + wv;
    float4 vr = *(const float4*)(C + (size_t)row * KDIM + 4*lane);
    float4 vi = *(const float4*)(C + (size_t)row * KDIM + 256 + 4*lane);
    float I0 = vr.x*vr.x + vi.x*vi.x;
    float I1 = vr.y*vr.y + vi.y*vi.y;
    float I2 = vr.z*vr.z + vi.z*vi.z;
    float I3 = vr.w*vr.w + vi.w*vi.w;
    float ss = I0*I0 + I1*I1 + I2*I2 + I3*I3;
#pragma unroll
    for (int d = 1; d < 64; d <<= 1) ss += __shfl_xor(ss, d, 64);
    float inv = 1.0f / fmaxf(sqrtf(ss), 1e-12f);
    float* o = out + (size_t)row * 10;
    if (lane == 0)      { o[0]=I0*inv; o[1]=I1*inv; o[2]=I2*inv; o[3]=I3*inv; }
    else if (lane == 1) { o[4]=I0*inv; o[5]=I1*inv; o[6]=I2*inv; o[7]=I3*inv; }
    else if (lane == 2) { o[8]=I0*inv; o[9]=I1*inv; }
}

extern "C" void kernel_launch(void* const* d_in, const int* in_sizes, int n_in,
                              void* d_out, int out_size, void* d_ws, size_t ws_size,
                              hipStream_t stream)
{
    const float* x_real = (const float*)d_in[0];
    const float* x_imag = (const float*)d_in[1];
    const float* theta  = (const float*)d_in[2];
    const float* phi    = (const float*)d_in[3];
    const float* gamma  = (const float*)d_in[4];

    // ws layout (fp32 first, then bf16; all 16B-aligned)
    float* coef = (float*)d_ws;                                    // 786432 f
    float* gexp = coef + (size_t)NITER * NWG * NPAIR * 8;          // 1536 f
    float* Cbuf = gexp + (size_t)NITER * NWG * 2;                  // 8192*512 f
    unsigned short* Bmat = (unsigned short*)(Cbuf + (size_t)NBATCH * KDIM); // 3*512*512 bf16
    unsigned short* xbig = Bmat + (size_t)NITER * KDIM * KDIM;     // 8192*512 bf16

    precompute_kernel<<<(NITER * NWG * NPAIR + 255) / 256, 256, 0, stream>>>(
        theta, phi, gamma, coef, gexp);

    propagate_kernel<<<NITER * 32, 256, 0, stream>>>(coef, gexp, Bmat);

    convert_kernel<<<NBATCH * NWG / 256, 256, 0, stream>>>(x_real, x_imag, xbig);

    dim3 ggrid(NBATCH / BM, KDIM / BN);
    for (int it = 0; it < NITER; ++it) {
        gemm_kernel<<<ggrid, 256, 0, stream>>>(
            xbig, Bmat + (size_t)it * KDIM * KDIM, Cbuf);
        if (it != NITER - 1)
            nonlin_kernel<<<NBATCH * NWG / 256, 256, 0, stream>>>(Cbuf, xbig);
    }

    final_kernel<<<NBATCH / 4, 256, 0, stream>>>(Cbuf, (float*)d_out);
}

// Round 4
// 191.091 us; speedup vs baseline: 3.4677x; 1.2820x over previous
//
#include <hip/hip_runtime.h>
#include <math.h>

#define NWG 256
#define NPAIR 128
#define NITER 3
#define NBATCH 8192
#define KDIM 512
#define MSZ (512*512)   // elems per embedded matrix

typedef __attribute__((ext_vector_type(8))) short short8;
typedef __attribute__((ext_vector_type(4))) float floatx4;

static __device__ __forceinline__ unsigned short f2bf(float f) {
    unsigned int u = __float_as_uint(f);
    unsigned int r = (u + 0x7fffu + ((u >> 16) & 1u)) >> 16;
    return (unsigned short)r;
}
static __device__ __forceinline__ float bf2f(unsigned short h) {
    return __uint_as_float(((unsigned int)h) << 16);
}
static __device__ __forceinline__ void bsplit(float v, unsigned short &h, unsigned short &l) {
    h = f2bf(v);
    l = f2bf(v - bf2f(h));
}
static __device__ __forceinline__ void async16(const void* g, void* l) {
    __builtin_amdgcn_global_load_lds(
        (const __attribute__((address_space(1))) unsigned int*)g,
        (__attribute__((address_space(3))) unsigned int*)l, 16, 0, 0);
}

static __device__ __forceinline__ void apply2(
    float &x0r, float &x0i, float &x1r, float &x1i,
    const float4 a, const float4 b)
{
    float y0r = a.x*x0r - a.y*x0i + a.z*x1r - a.w*x1i;
    float y0i = a.x*x0i + a.y*x0r + a.z*x1i + a.w*x1r;
    float y1r = b.x*x0r - b.y*x0i + b.z*x1r - b.w*x1i;
    float y1i = b.x*x0i + b.y*x0r + b.z*x1i + b.w*x1r;
    x0r = y0r; x0i = y0i; x1r = y1r; x1i = y1i;
}

// coef: rows (A,B),(C,D); coefT: transposed rows (A,C),(B,D); gexp: {cos,sin}
__global__ void precompute_kernel(const float* __restrict__ theta,
                                  const float* __restrict__ phi,
                                  const float* __restrict__ gamma,
                                  float* __restrict__ coef,
                                  float* __restrict__ coefT,
                                  float* __restrict__ gexp)
{
    int idx = blockIdx.x * blockDim.x + threadIdx.x;
    if (idx < NITER * NWG * NPAIR) {
        float h  = 0.5f * theta[idx];
        float ph = phi[idx];
        float sh = sinf(h),  ch = cosf(h);
        float sp = sinf(ph), cp = cosf(ph);
        float pr = -sh, pii = ch;            // pre = i*exp(i*h)
        float qr = pr*cp - pii*sp;           // pre*exp(i*ph)
        float qi = pr*sp + pii*cp;
        float Ar = qr*sh,  Ai = qi*sh;
        float Br = pr*ch,  Bi = pii*ch;
        float Cr = qr*ch,  Ci = qi*ch;
        float Dr = -pr*sh, Di = -pii*sh;
        float4* o = (float4*)coef + (size_t)idx * 2;
        o[0] = make_float4(Ar,Ai,Br,Bi);
        o[1] = make_float4(Cr,Ci,Dr,Di);
        float4* ot = (float4*)coefT + (size_t)idx * 2;
        ot[0] = make_float4(Ar,Ai,Cr,Ci);
        ot[1] = make_float4(Br,Bi,Dr,Di);
    }
    if (idx < NITER * NWG) {
        float g = gamma[idx];
        gexp[idx*2]   = cosf(g);
        gexp[idx*2+1] = sinf(g);
    }
}

// 12 groups (it,chunk). chunk even: forward (S=Q^T); odd: reverse-transposed (S=Q);
// chunk 3 starts with gamma (S3=G*Q3). Chunks 1,2 are B-operands of the compose
// GEMMs: stored as CONJUGATE embedding [[Re,+Im],[-Im,Re]] so that in real
// arithmetic A*B^T = E(Sa)*E(conj Sb)^T = E(Sa*Sb^T)   [E(X)^T == E(X^H)].
__global__ void propagate_kernel(const float* __restrict__ coef,
                                 const float* __restrict__ coefT,
                                 const float* __restrict__ gexp,
                                 unsigned short* __restrict__ chunkH,
                                 unsigned short* __restrict__ chunkL)
{
    const int lane = threadIdx.x & 63;
    const int wv   = threadIdx.x >> 6;
    const int grp  = blockIdx.x >> 6;          // 0..11
    const int it   = grp >> 2, c = grp & 3;
    const int row  = (blockIdx.x & 63) * 4 + wv;
    const bool rev = (c & 1);
    const bool cj  = (c == 1) || (c == 2);     // conjugate-embedded storage

    float xr[4], xi[4];
    float gc = 1.0f, gs = 0.0f;
    if (c == 3) { gc = gexp[(it*NWG + row)*2]; gs = gexp[(it*NWG + row)*2 + 1]; }
#pragma unroll
    for (int e = 0; e < 4; ++e) {
        bool on = (4*lane + e) == row;
        xr[e] = on ? gc : 0.0f;
        xi[e] = on ? gs : 0.0f;
    }

    const float4* cb = (const float4*)(rev ? coefT : coef)
                     + ((size_t)(it*NWG + c*64) * NPAIR) * 2;
    int sp0 = rev ? 63 : 0;
    const float4* p = cb + ((size_t)sp0 * NPAIR + 2*lane) * 2;
    float4 c0a = p[0], c0b = p[1], c1a = p[2], c1b = p[3];

    for (int s = 0; s < 64; ++s) {
        int sn  = (s + 1 < 64) ? s + 1 : s;
        int spn = rev ? 63 - sn : sn;
        const float4* np = cb + ((size_t)spn * NPAIR + 2*lane) * 2;
        float4 n0a = np[0], n0b = np[1], n1a = np[2], n1b = np[3];

        int sp = rev ? 63 - s : s;
        if ((sp & 1) == 0) {
            apply2(xr[0], xi[0], xr[1], xi[1], c0a, c0b);
            apply2(xr[2], xi[2], xr[3], xi[3], c1a, c1b);
        } else {
            float tr = __shfl_down(xr[0], 1, 64);
            float ti = __shfl_down(xi[0], 1, 64);
            apply2(xr[1], xi[1], xr[2], xi[2], c0a, c0b);
            float x3r = xr[3], x3i = xi[3];
            float y3r = c1a.x*x3r - c1a.y*x3i + c1a.z*tr - c1a.w*ti;
            float y3i = c1a.x*x3i + c1a.y*x3r + c1a.z*ti + c1a.w*tr;
            float ynr = c1b.x*x3r - c1b.y*x3i + c1b.z*tr - c1b.w*ti;
            float yni = c1b.x*x3i + c1b.y*x3r + c1b.z*ti + c1b.w*tr;
            float rr = __shfl_up(ynr, 1, 64);
            float ri = __shfl_up(yni, 1, 64);
            if (lane != 63) { xr[3] = y3r; xi[3] = y3i; }
            if (lane != 0)  { xr[0] = rr;  xi[0] = ri; }
        }
        c0a = n0a; c0b = n0b; c1a = n1a; c1b = n1b;
    }

    unsigned short* bh = chunkH + (size_t)grp * MSZ;
    unsigned short* bl = chunkL + (size_t)grp * MSZ;
    ushort4 reH, reL, imH, imL, nimH, nimL;
    unsigned short h, l;
#pragma unroll
    for (int e = 0; e < 4; ++e) {
        bsplit(xr[e], h, l);  ((unsigned short*)&reH)[e]  = h; ((unsigned short*)&reL)[e]  = l;
        bsplit(xi[e], h, l);  ((unsigned short*)&imH)[e]  = h; ((unsigned short*)&imL)[e]  = l;
        bsplit(-xi[e], h, l); ((unsigned short*)&nimH)[e] = h; ((unsigned short*)&nimL)[e] = l;
    }
    // plain:  [[Re, -Im],[ Im, Re]] ; conj: [[Re, +Im],[-Im, Re]]
    ushort4 urH = cj ? imH : nimH, urL = cj ? imL : nimL;   // upper-right
    ushort4 llH = cj ? nimH : imH, llL = cj ? nimL : imL;   // lower-left
    *(ushort4*)(bh + (size_t)row*KDIM + 4*lane)             = reH;
    *(ushort4*)(bh + (size_t)row*KDIM + 256 + 4*lane)       = urH;
    *(ushort4*)(bh + (size_t)(row+256)*KDIM + 4*lane)       = llH;
    *(ushort4*)(bh + (size_t)(row+256)*KDIM + 256 + 4*lane) = reH;
    *(ushort4*)(bl + (size_t)row*KDIM + 4*lane)             = reL;
    *(ushort4*)(bl + (size_t)row*KDIM + 256 + 4*lane)       = urL;
    *(ushort4*)(bl + (size_t)(row+256)*KDIM + 4*lane)       = llL;
    *(ushort4*)(bl + (size_t)(row+256)*KDIM + 256 + 4*lane) = reL;
}

// C = Ah*Bh^T + Ah*Bl^T + Al*Bh^T  (512x512, 64x64 tiles).
// mode0: z=it*2+wh. wh0: Pa^T = S0*S1^T (stored CONJUGATED: it is the B-operand
//        of mode1). wh1: Pb = S3*S2^T (stored plain). Outputs hi/lo split.
// mode1: z=it: E(M) = Pb * (Pa^T)^T -> bmat (single bf16)
__global__ __launch_bounds__(256, 2) void compose_kernel(
    const unsigned short* __restrict__ srcH, const unsigned short* __restrict__ srcL,
    unsigned short* __restrict__ outH, unsigned short* __restrict__ outL,
    unsigned short* __restrict__ bmat, int mode)
{
    __shared__ unsigned short sAh[2048], sAl[2048], sBh[2048], sBl[2048];
    const int z = blockIdx.z;
    const unsigned short *Ah, *Al, *Bh, *Bl;
    if (mode == 0) {
        int it = z >> 1, wh = z & 1;
        int ai = it*4 + (wh ? 3 : 0), bi = it*4 + (wh ? 2 : 1);
        Ah = srcH + (size_t)ai*MSZ; Al = srcL + (size_t)ai*MSZ;
        Bh = srcH + (size_t)bi*MSZ; Bl = srcL + (size_t)bi*MSZ;
    } else {
        Ah = srcH + (size_t)(2*z+1)*MSZ; Al = srcL + (size_t)(2*z+1)*MSZ;
        Bh = srcH + (size_t)(2*z)*MSZ;   Bl = srcL + (size_t)(2*z)*MSZ;
    }
    const int tid = threadIdx.x, lane = tid & 63, wv = tid >> 6;
    const int quad = lane >> 4, l16 = lane & 15;
    const int m0 = blockIdx.x * 64, n0 = blockIdx.y * 64;
    const unsigned short* src = (wv==0)?Ah:(wv==1)?Al:(wv==2)?Bh:Bl;
    unsigned short* dst = (wv==0)?sAh:(wv==1)?sAl:(wv==2)?sBh:sBl;
    const int r0 = (wv < 2) ? m0 : n0;
    const int trowb = lane >> 2, tcol = (lane & 3) * 8;

    floatx4 acc[4] = {};
    for (int kt = 0; kt < KDIM; kt += 32) {
        __syncthreads();
#pragma unroll
        for (int i = 0; i < 4; ++i)
            async16(src + (size_t)(r0 + i*16 + trowb)*KDIM + kt + tcol,
                    dst + i*512 + lane*8);
        __syncthreads();
        short8 ah = *(const short8*)&sAh[(16*wv + l16)*32 + quad*8];
        short8 al = *(const short8*)&sAl[(16*wv + l16)*32 + quad*8];
#pragma unroll
        for (int ni = 0; ni < 4; ++ni) {
            short8 bh = *(const short8*)&sBh[(16*ni + l16)*32 + quad*8];
            short8 bl = *(const short8*)&sBl[(16*ni + l16)*32 + quad*8];
            acc[ni] = __builtin_amdgcn_mfma_f32_16x16x32_bf16(ah, bh, acc[ni], 0,0,0);
            acc[ni] = __builtin_amdgcn_mfma_f32_16x16x32_bf16(ah, bl, acc[ni], 0,0,0);
            acc[ni] = __builtin_amdgcn_mfma_f32_16x16x32_bf16(al, bh, acc[ni], 0,0,0);
        }
    }
#pragma unroll
    for (int ni = 0; ni < 4; ++ni)
#pragma unroll
        for (int rg = 0; rg < 4; ++rg) {
            int r = m0 + 16*wv + quad*4 + rg;
            int cc = n0 + 16*ni + l16;
            float v = acc[ni][rg];
            if (mode == 0) {
                // wh==0 (z even): store conjugate embedding -> negate Im quadrants
                float vs = (((z & 1) == 0) && ((r >= 256) != (cc >= 256))) ? -v : v;
                unsigned short h, l; bsplit(vs, h, l);
                outH[(size_t)z*MSZ + (size_t)r*KDIM + cc] = h;
                outL[(size_t)z*MSZ + (size_t)r*KDIM + cc] = l;
            } else {
                bmat[(size_t)z*MSZ + (size_t)r*KDIM + cc] = f2bf(v);
            }
        }
}

__global__ void convert_kernel(const float* __restrict__ xre,
                               const float* __restrict__ xim,
                               unsigned short* __restrict__ xb)
{
    int idx = blockIdx.x * 256 + threadIdx.x;
    int b = idx >> 8, j = idx & 255;
    xb[(size_t)b * KDIM + j]       = f2bf(xre[idx]);
    xb[(size_t)b * KDIM + 256 + j] = f2bf(xim[idx]);
}

// out[b][n] = sum_k x[b][k]*Bm[n][k]. 64x128 tile; tile rows of Bm: {n0..n0+63}
// real rows, {n0+256..n0+319} imag rows -> in-register (re,im) pairing.
// mode 0/1: EO nonlin -> bf16 xout ; mode 2: intensity -> fp32 Iout.
__global__ __launch_bounds__(256, 2) void gemm_kernel(
    const unsigned short* __restrict__ A, const unsigned short* __restrict__ Bm,
    int mode, unsigned short* __restrict__ xout, float* __restrict__ Iout)
{
    __shared__ unsigned short sA[64*32];
    __shared__ unsigned short sB[128*32];
    const int tid = threadIdx.x, lane = tid & 63, wv = tid >> 6;
    const int quad = lane >> 4, l16 = lane & 15;
    const int m0 = blockIdx.x * 64, n0 = blockIdx.y * 64;
    const int trowb = lane >> 2, tcol = (lane & 3) * 8;

    floatx4 acc[8] = {};
    for (int kt = 0; kt < KDIM; kt += 32) {
        __syncthreads();
        async16(A + (size_t)(m0 + 16*wv + trowb)*KDIM + kt + tcol,
                &sA[wv*512 + lane*8]);
#pragma unroll
        for (int j = 0; j < 2; ++j) {
            int trow = 32*wv + 16*j + trowb;
            int grow = (trow < 64) ? (n0 + trow) : (n0 + trow + 192);
            async16(Bm + (size_t)grow*KDIM + kt + tcol,
                    &sB[(32*wv + 16*j)*32 + lane*8]);
        }
        __syncthreads();
        short8 a = *(const short8*)&sA[(16*wv + l16)*32 + quad*8];
#pragma unroll
        for (int ni = 0; ni < 8; ++ni) {
            short8 b = *(const short8*)&sB[(16*ni + l16)*32 + quad*8];
            acc[ni] = __builtin_amdgcn_mfma_f32_16x16x32_bf16(a, b, acc[ni], 0,0,0);
        }
    }
#pragma unroll
    for (int ni = 0; ni < 4; ++ni)
#pragma unroll
        for (int rg = 0; rg < 4; ++rg) {
            int row = m0 + 16*wv + quad*4 + rg;
            int cc  = n0 + 16*ni + l16;
            float yr = acc[ni][rg], yi = acc[ni+4][rg];
            if (mode == 2) {
                Iout[(size_t)row*256 + cc] = yr*yr + yi*yi;
            } else {
                float I = yr*yr + yi*yi;
                float phase = 0.078539816339744831f * I + 1.5707963267948966f;
                float sp, cp; __sincosf(phase, &sp, &cp);
                float f = 0.94868329805051381f * cp;
                xout[(size_t)row*KDIM + cc]       = f2bf(f*(cp*yr + sp*yi));
                xout[(size_t)row*KDIM + cc + 256] = f2bf(f*(cp*yi - sp*yr));
            }
        }
}

__global__ void final_kernel(const float* __restrict__ Ibuf,
                             float* __restrict__ out)
{
    const int lane = threadIdx.x & 63;
    const int wv   = threadIdx.x >> 6;
    const int row  = blockIdx.x * 4 + wv;
    float4 v = *(const float4*)(Ibuf + (size_t)row * 256 + 4*lane);
    float ss = v.x*v.x + v.y*v.y + v.z*v.z + v.w*v.w;
#pragma unroll
    for (int d = 1; d < 64; d <<= 1) ss += __shfl_xor(ss, d, 64);
    float inv = 1.0f / fmaxf(sqrtf(ss), 1e-12f);
    float* o = out + (size_t)row * 10;
    if (lane == 0)      { o[0]=v.x*inv; o[1]=v.y*inv; o[2]=v.z*inv; o[3]=v.w*inv; }
    else if (lane == 1) { o[4]=v.x*inv; o[5]=v.y*inv; o[6]=v.z*inv; o[7]=v.w*inv; }
    else if (lane == 2) { o[8]=v.x*inv; o[9]=v.y*inv; }
}

extern "C" void kernel_launch(void* const* d_in, const int* in_sizes, int n_in,
                              void* d_out, int out_size, void* d_ws, size_t ws_size,
                              hipStream_t stream)
{
    const float* x_real = (const float*)d_in[0];
    const float* x_imag = (const float*)d_in[1];
    const float* theta  = (const float*)d_in[2];
    const float* phi    = (const float*)d_in[3];
    const float* gamma  = (const float*)d_in[4];

    char* ws = (char*)d_ws;
    float* coef  = (float*)(ws + 0);              // 3 MB   [precompute->propagate]
    float* coefT = (float*)(ws + 3145728);        // 3 MB
    float* gexp  = (float*)(ws + 6291456);        // 6 KB
    unsigned short* chunkH = (unsigned short*)(ws + 6297600);   // 6 MB
    unsigned short* chunkL = (unsigned short*)(ws + 12589056);  // 6 MB
    unsigned short* PH   = (unsigned short*)(ws + 0);           // 3 MB (alias coef)
    unsigned short* PL   = (unsigned short*)(ws + 3145728);     // 3 MB (alias coefT)
    unsigned short* xbuf0 = (unsigned short*)(ws + 6297600);    // 8 MB (alias chunks)
    unsigned short* xbuf1 = (unsigned short*)(ws + 14686208);   // 8 MB
    float* Ibuf = (float*)(ws + 14686208);                      // 8 MB (alias xbuf1)
    unsigned short* Bmat = (unsigned short*)(ws + 23074816);    // 1.5 MB

    precompute_kernel<<<(NITER*NWG*NPAIR + 255)/256, 256, 0, stream>>>(
        theta, phi, gamma, coef, coefT, gexp);

    propagate_kernel<<<768, 256, 0, stream>>>(coef, coefT, gexp, chunkH, chunkL);

    compose_kernel<<<dim3(8,8,6), 256, 0, stream>>>(chunkH, chunkL, PH, PL, Bmat, 0);
    compose_kernel<<<dim3(8,8,3), 256, 0, stream>>>(PH, PL, PH, PL, Bmat, 1);

    convert_kernel<<<NBATCH*NWG/256, 256, 0, stream>>>(x_real, x_imag, xbuf0);

    gemm_kernel<<<dim3(128,4), 256, 0, stream>>>(xbuf0, Bmat,           0, xbuf1, (float*)nullptr);
    gemm_kernel<<<dim3(128,4), 256, 0, stream>>>(xbuf1, Bmat + MSZ,     1, xbuf0, (float*)nullptr);
    gemm_kernel<<<dim3(128,4), 256, 0, stream>>>(xbuf0, Bmat + 2*MSZ,   2, (unsigned short*)nullptr, Ibuf);

    final_kernel<<<NBATCH/4, 256, 0, stream>>>(Ibuf, (float*)d_out);
}